// Round 6
// baseline (10082.597 us; speedup 1.0000x reference)
//
#include <hip/hip_runtime.h>
#include <hip/hip_bf16.h>
#include <cstddef>

#define B_ 128
#define T_ 256
#define H_ 512
#define H4_ 2048

__device__ __forceinline__ float rcp_f(float x) { return __builtin_amdgcn_rcpf(x); }
__device__ __forceinline__ float sigf(float x) { return rcp_f(1.0f + __expf(-x)); }
__device__ __forceinline__ float tanh_f(float x) {
  float p = __expf(x + x);
  return fmaf(-2.0f, rcp_f(1.0f + p), 1.0f);
}
__device__ __forceinline__ float4 ld4(const float* p) { return *reinterpret_cast<const float4*>(p); }
__device__ __forceinline__ void st4(float* p, float4 v) { *reinterpret_cast<float4*>(p) = v; }
__device__ __forceinline__ void fma4(float4& a, float s, float4 w) {
  a.x = fmaf(s, w.x, a.x); a.y = fmaf(s, w.y, a.y);
  a.z = fmaf(s, w.z, a.z); a.w = fmaf(s, w.w, a.w);
}

// ---- agent-scope (device-coherent) accessors for mutable cross-WG data ----
__device__ __forceinline__ float ald1(const float* p) {
  return __hip_atomic_load(p, __ATOMIC_RELAXED, __HIP_MEMORY_SCOPE_AGENT);
}
__device__ __forceinline__ void ast1(float* p, float v) {
  __hip_atomic_store(p, v, __ATOMIC_RELAXED, __HIP_MEMORY_SCOPE_AGENT);
}
__device__ __forceinline__ float2 ald2(const float* p) {
  unsigned long long v = __hip_atomic_load((const unsigned long long*)p,
                                           __ATOMIC_RELAXED, __HIP_MEMORY_SCOPE_AGENT);
  union { unsigned long long u; float2 f; } c; c.u = v; return c.f;
}

// fp16 helpers
union H4 { ushort4 u; _Float16 h[4]; };
union H8 { int4 v; _Float16 h[8]; };
__device__ __forceinline__ void sth4(_Float16* p, float4 v) {
  H4 c;
  c.h[0] = (_Float16)v.x; c.h[1] = (_Float16)v.y;
  c.h[2] = (_Float16)v.z; c.h[3] = (_Float16)v.w;
  *reinterpret_cast<ushort4*>(p) = c.u;
}

// ---------------- workspace layout (float offsets) ----------------
// w1e fp16 = 32768*512 halfs = 16,777,216 halfs = 8,388,608 floats
#define W1EH_OFF  0ull           // ends  8388608
#define WPACK_OFF 8388608ull     // 1572864 floats: Wpack[g][k=768][c=8] fp32 -> ends 9961472
#define W2H_OFF   9961472ull     // 262144 halfs = 131072 floats -> ends 10092544
#define HP_OFF    10092544ull    // 131072   htr[2][256 k2][128 b][2]          -> ends 10223616
#define HROW_OFF  10223616ull    // 65536    hrow[128 b][512]                  -> ends 10289152
#define EP_OFF    10289152ull    // 32768    etr[128 t2][128 b][2]             -> ends 10321920
#define W2D_OFF   10321920ull    // 65536    w2d[128 b][512]                   -> ends 10387456
#define D2_OFF    10387456ull    // 512      d2[2][128 b][2]                   -> ends 10387968
#define CNT_OFF   10387968ull    // 1024 uints

// ---------------- w1e = enc[32768,512] @ W1[512,512], output fp16 ----------------
__global__ __launch_bounds__(256) void w1e_kernel(const float* __restrict__ A,
                                                  const float* __restrict__ Bw,
                                                  _Float16* __restrict__ C) {
  __shared__ float As[32][68];
  __shared__ float Bs[32][68];
  const int i0 = blockIdx.x * 64;
  const int j0 = blockIdx.y * 64;
  const int tx = threadIdx.x & 15, ty = threadIdx.x >> 4;
  float4 acc0 = make_float4(0,0,0,0), acc1 = acc0, acc2 = acc0, acc3 = acc0;
  for (int k0 = 0; k0 < H_; k0 += 32) {
#pragma unroll
    for (int q = 0; q < 2; q++) {
      int idx = q * 256 + threadIdx.x;
      int ai = idx >> 3, ak = (idx & 7) << 2;
      float4 av = ld4(A + (size_t)(i0 + ai) * H_ + k0 + ak);
      As[ak][ai] = av.x; As[ak + 1][ai] = av.y; As[ak + 2][ai] = av.z; As[ak + 3][ai] = av.w;
      int bk = idx >> 4, bj = (idx & 15) << 2;
      st4(&Bs[bk][bj], ld4(Bw + (size_t)(k0 + bk) * H_ + j0 + bj));
    }
    __syncthreads();
#pragma unroll
    for (int kk = 0; kk < 32; kk++) {
      float4 a = ld4(&As[kk][ty << 2]);
      float4 bv = ld4(&Bs[kk][tx << 2]);
      fma4(acc0, a.x, bv); fma4(acc1, a.y, bv); fma4(acc2, a.z, bv); fma4(acc3, a.w, bv);
    }
    __syncthreads();
  }
  size_t base = (size_t)(i0 + (ty << 2)) * H_ + j0 + (tx << 2);
  sth4(&C[base], acc0); sth4(&C[base + H_], acc1);
  sth4(&C[base + 2 * H_], acc2); sth4(&C[base + 3 * H_], acc3);
}

// ---------------- pack Wk/Wr fp32 per-WG + W2 fp16 + zero counters ----------------
__global__ __launch_bounds__(256) void pack_kernel(const float* __restrict__ Wk,
                                                   const float* __restrict__ Wr,
                                                   const float* __restrict__ W2,
                                                   float* __restrict__ Wpack,
                                                   _Float16* __restrict__ W2h,
                                                   unsigned* __restrict__ cnt) {
  const int g = blockIdx.x, tid = threadIdx.x;
#pragma unroll
  for (int it = 0; it < 24; ++it) {
    int idx = it * 256 + tid;            // 0..6143
    int k = idx >> 3, c = idx & 7;       // c = gate*2 + jj
    int col = (c >> 1) * 512 + 2 * g + (c & 1);
    float v = (k < 256) ? Wk[(size_t)k * H4_ + col] : Wr[(size_t)(k - 256) * H4_ + col];
    Wpack[((size_t)g * 768 + k) * 8 + c] = v;
  }
#pragma unroll
  for (int it = 0; it < 4; ++it) {
    int idx = it * 65536 + g * 256 + tid;
    W2h[idx] = (_Float16)W2[idx];
  }
  if (g == 0) {
#pragma unroll
    for (int i = 0; i < 4; ++i) cnt[i * 256 + tid] = 0u;
  }
}

// ---------------- low-contention two-level grid barrier (no fences) ----------------
__device__ __forceinline__ void gridbar(unsigned* cnt, unsigned& phase, int tid, int wg) {
  asm volatile("s_waitcnt vmcnt(0)" ::: "memory");  // every wave: own stores at LLC
  __syncthreads();
  if (tid == 0) {
    unsigned r1 = __hip_atomic_fetch_add(&cnt[(wg & 31) * 16], 1u,
                                         __ATOMIC_RELAXED, __HIP_MEMORY_SCOPE_AGENT);
    if (r1 == phase * 8u + 7u) {
      unsigned r2 = __hip_atomic_fetch_add(&cnt[512], 1u,
                                           __ATOMIC_RELAXED, __HIP_MEMORY_SCOPE_AGENT);
      if (r2 == phase * 32u + 31u) {
#pragma unroll
        for (int i = 0; i < 8; ++i)
          __hip_atomic_store(&cnt[768 + i * 16], phase + 1u,
                             __ATOMIC_RELAXED, __HIP_MEMORY_SCOPE_AGENT);
      }
    }
    const unsigned* rel = &cnt[768 + (wg >> 5) * 16];
    while (__hip_atomic_load(rel, __ATOMIC_RELAXED, __HIP_MEMORY_SCOPE_AGENT) <= phase)
      __builtin_amdgcn_s_sleep(2);
  }
  __syncthreads();
  ++phase;
}

// ---------------- persistent decoder: 256 WGs x 1024 thr, 1 WG/CU ----------------
__global__ __launch_bounds__(1024, 4) void decoder_persistent(
    const _Float16* __restrict__ w1eh, const float* __restrict__ Wpack,
    const _Float16* __restrict__ W2h, const float* __restrict__ Vv,
    const float* __restrict__ bias, const float* __restrict__ h0,
    const float* __restrict__ c0,
    float* __restrict__ htr,   // [2][256][128][2]
    float* __restrict__ hrow,  // [128][512]
    float* __restrict__ etr,   // [128][128][2]
    float* __restrict__ w2dA,  // [128][512]
    float* __restrict__ d2,    // [2][128][2]
    unsigned* __restrict__ cnt,
    float* __restrict__ out) {
  // 84KB LDS: forces 1 WG/CU -> all 256 WGs co-resident (barrier deadlock-free)
  __shared__ float smem[21504];
  float* zred     = smem;            // gates: [8][128][12]; w2d: [16][256]
  float* zfin     = smem + 12288;    // [128][8]
  float* c_lds    = smem + 13312;    // [128][2]
  float* bias_lds = smem + 13568;    // [8]
  float* dred     = smem + 13576;    // [16]

  const int g = blockIdx.x;
  const int tid = threadIdx.x;
  const int bl = tid & 127;
  const int ksu = __builtin_amdgcn_readfirstlane(tid >> 7);  // 0..7 k-split
  const int wv = tid >> 6, ln = tid & 63;
  const int sb = g >> 1;            // batch row (score & w2d phases)
  const int t0 = (g & 1) << 7;      // t half
  unsigned phase = 0;
  float epv[8];                     // lane0: this WG's e values (prev step)

  // ---- init ----
  if (tid < 256) {
    int b = tid >> 1, jj = tid & 1;
    c_lds[b * 2 + jj] = c0[(size_t)b * H_ + 2 * g + jj];
    ast1(htr + 65536 + ((size_t)g * 128 + b) * 2 + jj, h0[(size_t)b * H_ + 2 * g + jj]);
    if (g == 0) ast1(d2 + 256 + tid, 0.5f);   // d(-1): pair sums to 1
  }
  if (tid < 8) bias_lds[tid] = bias[(tid >> 1) * 512 + 2 * g + (tid & 1)];
  if (g < 128) ast1(etr + g * 256 + tid, 1.0f);   // e(-1) = 1
  gridbar(cnt, phase, tid, g);

  const float4 v0 = ld4(Vv + (ln << 3));
  const float4 v1 = ld4(Vv + (ln << 3) + 4);

  for (int s = 0; s < 256; ++s) {
    const float* hin = htr + ((s + 1) & 1) * 65536;
    float* hout = htr + (s & 1) * 65536;
    const float* dPrev = d2 + ((s + 1) & 1) * 256;
    float* dCur = d2 + (s & 1) * 256;

    // ================= gates =================
    {
      float2 dd = ald2(dPrev + bl * 2);
      float rd = rcp_f(dd.x + dd.y);
      float4 accA = make_float4(0,0,0,0), accB = accA;
      // ---- e-part: preload all 16 uncached inputs, then FMA ----
      float2 e0[8], e1[8];
#pragma unroll
      for (int j = 0; j < 8; ++j) {
        int k2 = ksu * 2 + j * 16;
        e0[j] = ald2(etr + k2 * 256 + bl * 2);
        e1[j] = ald2(etr + k2 * 256 + 256 + bl * 2);
      }
#pragma unroll
      for (int j = 0; j < 8; ++j) {
        int kb = ksu * 4 + j * 32;
        const float* wp = Wpack + (((size_t)g * 768 + kb) << 3);
        float4 wa0 = ld4(wp),      wb0 = ld4(wp + 4);
        float4 wa1 = ld4(wp + 8),  wb1 = ld4(wp + 12);
        float4 wa2 = ld4(wp + 16), wb2 = ld4(wp + 20);
        float4 wa3 = ld4(wp + 24), wb3 = ld4(wp + 28);
        fma4(accA, e0[j].x, wa0); fma4(accB, e0[j].x, wb0);
        fma4(accA, e0[j].y, wa1); fma4(accB, e0[j].y, wb1);
        fma4(accA, e1[j].x, wa2); fma4(accB, e1[j].x, wb2);
        fma4(accA, e1[j].y, wa3); fma4(accB, e1[j].y, wb3);
      }
      accA.x *= rd; accA.y *= rd; accA.z *= rd; accA.w *= rd;
      accB.x *= rd; accB.y *= rd; accB.z *= rd; accB.w *= rd;
      // ---- h-part: two chunks of preload-16 + FMA ----
#pragma unroll
      for (int half = 0; half < 2; ++half) {
        float2 p0[8], p1[8];
#pragma unroll
        for (int j = 0; j < 8; ++j) {
          int k2 = ksu * 2 + (half * 8 + j) * 16;
          p0[j] = ald2(hin + k2 * 256 + bl * 2);
          p1[j] = ald2(hin + k2 * 256 + 256 + bl * 2);
        }
#pragma unroll
        for (int j = 0; j < 8; ++j) {
          int kb = ksu * 4 + (half * 8 + j) * 32;
          const float* wp = Wpack + (((size_t)g * 768 + 256 + kb) << 3);
          float4 wa0 = ld4(wp),      wb0 = ld4(wp + 4);
          float4 wa1 = ld4(wp + 8),  wb1 = ld4(wp + 12);
          float4 wa2 = ld4(wp + 16), wb2 = ld4(wp + 20);
          float4 wa3 = ld4(wp + 24), wb3 = ld4(wp + 28);
          fma4(accA, p0[j].x, wa0); fma4(accB, p0[j].x, wb0);
          fma4(accA, p0[j].y, wa1); fma4(accB, p0[j].y, wb1);
          fma4(accA, p1[j].x, wa2); fma4(accB, p1[j].x, wb2);
          fma4(accA, p1[j].y, wa3); fma4(accB, p1[j].y, wb3);
        }
      }
      float* zr = &zred[(ksu * 128 + bl) * 12];
      st4(zr, accA); st4(zr + 4, accB);
    }
    __syncthreads();
    {  // k-split reduce: 1024 thr = 128 b x 8 c
      int b = tid >> 3, cc = tid & 7;
      float zsum = bias_lds[cc];
#pragma unroll
      for (int k2 = 0; k2 < 8; ++k2) zsum += zred[(k2 * 128 + b) * 12 + cc];
      zfin[b * 8 + cc] = zsum;
    }
    __syncthreads();
    if (tid < 256) {  // LSTM epilogue: this WG's 2 h-cols
      int b = tid >> 1, jj = tid & 1;
      float zi = zfin[b * 8 + 0 + jj], zf = zfin[b * 8 + 2 + jj];
      float zg = zfin[b * 8 + 4 + jj], zo = zfin[b * 8 + 6 + jj];
      float cv = c_lds[b * 2 + jj];
      float cn = sigf(zf) * cv + sigf(zi) * tanh_f(zg);
      float hn = sigf(zo) * tanh_f(cn);
      c_lds[b * 2 + jj] = cn;
      ast1(hout + ((size_t)g * 128 + b) * 2 + jj, hn);
      ast1(hrow + (size_t)b * 512 + 2 * g + jj, hn);
    }
    gridbar(cnt, phase, tid, g);

    // ================= w2d (batch-split, fp16 weights) =================
    {
      const int colb = ((g & 1) << 8) + (ln << 2);
      const float* hb = hrow + (size_t)sb * 512 + (wv << 5);
      float hreg[32];
#pragma unroll
      for (int kk = 0; kk < 32; ++kk) hreg[kk] = ald1(hb + kk);
      float4 acc = make_float4(0,0,0,0);
#pragma unroll 8
      for (int kk = 0; kk < 32; ++kk) {
        H4 w; w.u = *reinterpret_cast<const ushort4*>(W2h + (size_t)((wv << 5) + kk) * 512 + colb);
        float4 wf = make_float4((float)w.h[0], (float)w.h[1], (float)w.h[2], (float)w.h[3]);
        fma4(acc, hreg[kk], wf);
      }
      st4(&zred[(wv << 8) + (ln << 2)], acc);
    }
    __syncthreads();
    if (tid < 256) {
      float sum = 0.0f;
#pragma unroll
      for (int w = 0; w < 16; ++w) sum += zred[(w << 8) + tid];
      ast1(w2dA + (size_t)sb * 512 + ((g & 1) << 8) + tid, sum);
    }
    gridbar(cnt, phase, tid, g);

    // ================= score (fp16 w1e, preloaded rows) =================
    {
      const float* wrow = w2dA + (size_t)sb * 512 + (ln << 3);
      float2 a0 = ald2(wrow), a1 = ald2(wrow + 2), a2 = ald2(wrow + 4), a3 = ald2(wrow + 6);
      float4 u0 = make_float4(a0.x, a0.y, a1.x, a1.y);
      float4 u1 = make_float4(a2.x, a2.y, a3.x, a3.y);
      float2 ddp = ald2(dPrev + sb * 2);
      float rdp = rcp_f(ddp.x + ddp.y);
      const _Float16* rowb = w1eh + (((size_t)sb * 256 + t0 + (wv << 3)) << 9) + (ln << 3);
      H8 raws[8];
#pragma unroll
      for (int r = 0; r < 8; ++r)
        raws[r].v = *reinterpret_cast<const int4*>(rowb + (size_t)r * 512);
      float sc[8];
#pragma unroll
      for (int r = 0; r < 8; ++r) {
        float a;
        a = tanh_f((float)raws[r].h[0] + u0.x) * v0.x;
        a = fmaf(tanh_f((float)raws[r].h[1] + u0.y), v0.y, a);
        a = fmaf(tanh_f((float)raws[r].h[2] + u0.z), v0.z, a);
        a = fmaf(tanh_f((float)raws[r].h[3] + u0.w), v0.w, a);
        a = fmaf(tanh_f((float)raws[r].h[4] + u1.x), v1.x, a);
        a = fmaf(tanh_f((float)raws[r].h[5] + u1.y), v1.y, a);
        a = fmaf(tanh_f((float)raws[r].h[6] + u1.z), v1.z, a);
        a = fmaf(tanh_f((float)raws[r].h[7] + u1.w), v1.w, a);
#pragma unroll
        for (int m = 32; m > 0; m >>= 1) a += __shfl_xor(a, m, 64);
        sc[r] = a;
      }
      if (ln == 0) {
        float dacc = 0.0f;
#pragma unroll
        for (int r = 0; r < 8; ++r) {
          int t = t0 + (wv << 3) + r;
          if (s > 0) out[(size_t)sb * 65536 + (size_t)(s - 1) * 256 + t] = epv[r] * rdp;
          float ev = __expf(sc[r]);
          epv[r] = ev;
          ast1(etr + (((t >> 1) << 7) + sb) * 2 + (t & 1), ev);
          dacc += ev;
        }
        dred[wv] = dacc;
      }
    }
    __syncthreads();
    if (tid == 0) {
      float sd = 0.0f;
#pragma unroll
      for (int k = 0; k < 16; ++k) sd += dred[k];
      ast1(dCur + sb * 2 + (g & 1), sd);
    }
    gridbar(cnt, phase, tid, g);
  }

  // ---- final: out row 255 (e of step 255 in regs; d(255) in buffer 1) ----
  {
    float2 ddf = ald2(d2 + 256 + sb * 2);
    float rdf = rcp_f(ddf.x + ddf.y);
    if (ln == 0) {
#pragma unroll
      for (int r = 0; r < 8; ++r) {
        int t = t0 + (wv << 3) + r;
        out[(size_t)sb * 65536 + 255ull * 256 + t] = epv[r] * rdf;
      }
    }
  }
}

extern "C" void kernel_launch(void* const* d_in, const int* in_sizes, int n_in,
                              void* d_out, int out_size, void* d_ws, size_t ws_size,
                              hipStream_t stream) {
  const float* enc  = (const float*)d_in[0];
  const float* h0   = (const float*)d_in[1];
  const float* c0   = (const float*)d_in[2];
  const float* W1   = (const float*)d_in[3];
  const float* W2   = (const float*)d_in[4];
  const float* V    = (const float*)d_in[5];
  const float* Wk   = (const float*)d_in[6];
  const float* Wr   = (const float*)d_in[7];
  const float* bias = (const float*)d_in[8];
  float* out = (float*)d_out;
  float* ws = (float*)d_ws;

  _Float16* w1eh = (_Float16*)(ws + W1EH_OFF);
  float* Wpack   = ws + WPACK_OFF;
  _Float16* W2h  = (_Float16*)(ws + W2H_OFF);
  float* htr     = ws + HP_OFF;
  float* hrow    = ws + HROW_OFF;
  float* etr     = ws + EP_OFF;
  float* w2dA    = ws + W2D_OFF;
  float* d2      = ws + D2_OFF;
  unsigned* cnt  = (unsigned*)(ws + CNT_OFF);

  pack_kernel<<<256, 256, 0, stream>>>(Wk, Wr, W2, Wpack, W2h, cnt);
  w1e_kernel<<<dim3(512, 8), 256, 0, stream>>>(enc, W1, w1eh);
  decoder_persistent<<<256, 1024, 0, stream>>>(w1eh, Wpack, W2h, V, bias, h0, c0,
                                               htr, hrow, etr, w2dA, d2, cnt, out);
}